// Round 9
// baseline (1627.532 us; speedup 1.0000x reference)
//
#include <hip/hip_runtime.h>

#define N_NODES 50000
#define N_GENES 256
#define N_EDGES 800000
#define NUM_ITERS 10
#define SCAN_BLK 1024
#define N_SCAN_BLKS ((N_NODES + SCAN_BLK - 1) / SCAN_BLK)   // 49

#define SLICE_G 32                    // genes/slice; bf16 slice = 3.2 MB < 4 MB L2
#define N_SLICES 8                    // one slice per XCD
#define PROP_GRID (12500 * 8)         // 12500 node-blocks (4 nodes) x 8 slices

typedef unsigned short u16;
struct u16x4 { u16 x, y, z, w; };

static __device__ __forceinline__ float bf2f(u16 b) {
    return __uint_as_float(((unsigned)b) << 16);
}
static __device__ __forceinline__ u16 f2bf(float f) {
    unsigned u = __float_as_uint(f);
    return (u16)((u + 0x7fffu + ((u >> 16) & 1u)) >> 16);   // RNE
}

// ---------------- CSR build (once per launch) -----------------------------

__global__ void hist_kernel(const int* __restrict__ dst, int* __restrict__ counts) {
    int e = blockIdx.x * blockDim.x + threadIdx.x;
    if (e < N_EDGES) atomicAdd(&counts[dst[e]], 1);
}

__global__ __launch_bounds__(SCAN_BLK) void scan1_kernel(
        const int* __restrict__ counts, int* __restrict__ offs,
        int* __restrict__ bsums) {
    int i = blockIdx.x * SCAN_BLK + threadIdx.x;
    int lane = threadIdx.x & 63, wid = threadIdx.x >> 6;
    int v = (i < N_NODES) ? counts[i] : 0;
    int x = v;
    #pragma unroll
    for (int o = 1; o < 64; o <<= 1) {
        int t = __shfl_up(x, o, 64);
        if (lane >= o) x += t;
    }
    __shared__ int wsum[16];
    if (lane == 63) wsum[wid] = x;
    __syncthreads();
    if (wid == 0 && lane < 16) {
        int y = wsum[lane];
        #pragma unroll
        for (int o = 1; o < 16; o <<= 1) {
            int t = __shfl_up(y, o, 64);
            if (lane >= o) y += t;
        }
        wsum[lane] = y;
    }
    __syncthreads();
    int pref = (wid > 0) ? wsum[wid - 1] : 0;
    int incl = x + pref;
    if (i < N_NODES) offs[i] = incl - v;
    if (threadIdx.x == SCAN_BLK - 1) bsums[blockIdx.x] = incl;
}

__global__ void scan2_kernel(const int* __restrict__ bsums,
                             int* __restrict__ bpref,
                             int* __restrict__ offs_total) {
    int lane = threadIdx.x;  // 64 threads
    int v = (lane < N_SCAN_BLKS) ? bsums[lane] : 0;
    int x = v;
    #pragma unroll
    for (int o = 1; o < 64; o <<= 1) {
        int t = __shfl_up(x, o, 64);
        if (lane >= o) x += t;
    }
    if (lane < N_SCAN_BLKS) bpref[lane] = x - v;
    if (lane == 63) offs_total[0] = x;
}

__global__ __launch_bounds__(SCAN_BLK) void scan3_kernel(
        int* __restrict__ offs, const int* __restrict__ bpref,
        int* __restrict__ cursor) {
    int i = blockIdx.x * SCAN_BLK + threadIdx.x;
    if (i < N_NODES) {
        int o = offs[i] + bpref[blockIdx.x];
        offs[i] = o;
        cursor[i] = o;
    }
}

// CSR payload: 4B/edge meta = u16 src | bf16(w) << 16
__global__ void scatter_kernel(const int* __restrict__ dst,
                               const int* __restrict__ src,
                               const float* __restrict__ w,
                               int* __restrict__ cursor,
                               unsigned* __restrict__ meta) {
    int e = blockIdx.x * blockDim.x + threadIdx.x;
    if (e < N_EDGES) {
        int d = dst[e];
        int p = atomicAdd(&cursor[d], 1);
        meta[p] = (unsigned)(u16)src[e] | ((unsigned)f2bf(w[e]) << 16);
    }
}

// x (f32 node-major) -> xs (bf16 slice-major [8][N][32]); 8 genes per thread
__global__ __launch_bounds__(256) void cvt_slice_kernel(const float* __restrict__ x,
                                                        u16* __restrict__ xs) {
    int base = (blockIdx.x * blockDim.x + threadIdx.x) * 8;
    if (base >= N_NODES * N_GENES) return;
    int node = base >> 8;
    int gene = base & 255;
    int slice = gene >> 5;
    int g = gene & 31;             // 8-aligned within slice
    float4 a = *reinterpret_cast<const float4*>(&x[base]);
    float4 b = *reinterpret_cast<const float4*>(&x[base + 4]);
    u16x4 r0 = { f2bf(a.x), f2bf(a.y), f2bf(a.z), f2bf(a.w) };
    u16x4 r1 = { f2bf(b.x), f2bf(b.y), f2bf(b.z), f2bf(b.w) };
    size_t o = (size_t)slice * (N_NODES * SLICE_G) + (size_t)node * SLICE_G + g;
    *reinterpret_cast<u16x4*>(&xs[o])     = r0;
    *reinterpret_cast<u16x4*>(&xs[o + 4]) = r1;
}

// ---------------- XCD-pinned sliced propagation ---------------------------
// Slice s (32 genes bf16 over all nodes = 3.2 MB) is touched only by blocks
// with blockIdx%8 == s -> one slice per XCD, fully L2-resident (also across
// iterations: each XCD re-reads its own previous writes). One wave per
// (node, slice); the wave gathers 8 EDGES PER INSTRUCTION: 8 groups x 8
// lanes x u16x4 (4 genes/lane -> 4 FMA/lane/gather, same density as the
// fast unsliced kernel). One 4B meta load per 64 edges + one bpermute per
// 8-edge batch supplies (src, w).

__global__ __launch_bounds__(256) void prop8_b(
        const u16* __restrict__ hin,   // [8][N][32]
        const u16* __restrict__ xs,    // [8][N][32]
        const int* __restrict__ offsets,
        const unsigned* __restrict__ meta,
        u16* __restrict__ out) {       // [8][N][32]
    int slice = blockIdx.x & 7;
    int node  = (blockIdx.x >> 3) * 4 + (threadIdx.x >> 6);  // 12500*4 = 50000
    int lane = threadIdx.x & 63;
    int sub = lane & 7;          // gene sublane: genes sub*4 .. sub*4+3
    int grp = lane >> 3;         // edge group 0..7
    const u16* hs = hin + (size_t)slice * (N_NODES * SLICE_G);

    int beg = offsets[node], end = offsets[node + 1];
    float a0 = 0.f, a1 = 0.f, a2 = 0.f, a3 = 0.f;

    for (int base = beg; base < end; base += 64) {
        int cnt = end - base;
        if (cnt > 64) cnt = 64;
        unsigned mv = 0;
        if (lane < cnt) mv = __builtin_nontemporal_load(&meta[base + lane]);
        int nb = (cnt + 7) >> 3;     // batches of 8 edges
        for (int b = 0; b < nb; ++b) {
            int eidx = b * 8 + grp;              // this group's edge slot
            unsigned m = __shfl(mv, eidx);       // (src | bf16w<<16); 0 if padded
            if (eidx < cnt) {
                float w = bf2f((u16)(m >> 16));
                int   s = (int)(m & 0xFFFFu);
                u16x4 r = *reinterpret_cast<const u16x4*>(&hs[(size_t)s * SLICE_G + sub * 4]);
                a0 += w * bf2f(r.x);
                a1 += w * bf2f(r.y);
                a2 += w * bf2f(r.z);
                a3 += w * bf2f(r.w);
            }
        }
    }

    // reduce across the 8 edge groups (gene sublane stays fixed)
    #pragma unroll
    for (int off = 8; off < 64; off <<= 1) {
        a0 += __shfl_xor(a0, off);
        a1 += __shfl_xor(a1, off);
        a2 += __shfl_xor(a2, off);
        a3 += __shfl_xor(a3, off);
    }

    if (grp == 0) {
        size_t o = (size_t)slice * (N_NODES * SLICE_G) + (size_t)node * SLICE_G + sub * 4;
        u16x4 ox = *reinterpret_cast<const u16x4*>(&xs[o]);
        u16x4 res;
        res.x = ox.x ? ox.x : f2bf(a0);   // x >= 0: bits==0 <=> value==0
        res.y = ox.y ? ox.y : f2bf(a1);
        res.z = ox.z ? ox.z : f2bf(a2);
        res.w = ox.w ? ox.w : f2bf(a3);
        *reinterpret_cast<u16x4*>(&out[o]) = res;
    }
}

// Final iteration: same structure, clamp with pristine f32 x, write f32
// node-major output.
__global__ __launch_bounds__(256) void prop8_final(
        const u16* __restrict__ hin,
        const float* __restrict__ x,
        const int* __restrict__ offsets,
        const unsigned* __restrict__ meta,
        float* __restrict__ out) {
    int slice = blockIdx.x & 7;
    int node  = (blockIdx.x >> 3) * 4 + (threadIdx.x >> 6);
    int lane = threadIdx.x & 63;
    int sub = lane & 7;
    int grp = lane >> 3;
    const u16* hs = hin + (size_t)slice * (N_NODES * SLICE_G);

    int beg = offsets[node], end = offsets[node + 1];
    float a0 = 0.f, a1 = 0.f, a2 = 0.f, a3 = 0.f;

    for (int base = beg; base < end; base += 64) {
        int cnt = end - base;
        if (cnt > 64) cnt = 64;
        unsigned mv = 0;
        if (lane < cnt) mv = __builtin_nontemporal_load(&meta[base + lane]);
        int nb = (cnt + 7) >> 3;
        for (int b = 0; b < nb; ++b) {
            int eidx = b * 8 + grp;
            unsigned m = __shfl(mv, eidx);
            if (eidx < cnt) {
                float w = bf2f((u16)(m >> 16));
                int   s = (int)(m & 0xFFFFu);
                u16x4 r = *reinterpret_cast<const u16x4*>(&hs[(size_t)s * SLICE_G + sub * 4]);
                a0 += w * bf2f(r.x);
                a1 += w * bf2f(r.y);
                a2 += w * bf2f(r.z);
                a3 += w * bf2f(r.w);
            }
        }
    }

    #pragma unroll
    for (int off = 8; off < 64; off <<= 1) {
        a0 += __shfl_xor(a0, off);
        a1 += __shfl_xor(a1, off);
        a2 += __shfl_xor(a2, off);
        a3 += __shfl_xor(a3, off);
    }

    if (grp == 0) {
        size_t xo = (size_t)node * N_GENES + slice * SLICE_G + sub * 4;
        float4 o = *reinterpret_cast<const float4*>(&x[xo]);
        float4 r;
        r.x = (o.x != 0.f) ? o.x : a0;
        r.y = (o.y != 0.f) ? o.y : a1;
        r.z = (o.z != 0.f) ? o.z : a2;
        r.w = (o.w != 0.f) ? o.w : a3;
        *reinterpret_cast<float4*>(&out[xo]) = r;
    }
}

// --------------------------------------------------------------------------

static inline size_t align_up(size_t x, size_t a) { return (x + a - 1) & ~(a - 1); }

extern "C" void kernel_launch(void* const* d_in, const int* in_sizes, int n_in,
                              void* d_out, int out_size, void* d_ws, size_t ws_size,
                              hipStream_t stream) {
    const float* x    = (const float*)d_in[0];   // [N_NODES, N_GENES]
    const int*   eidx = (const int*)d_in[1];     // [2, N_EDGES]: row0 = dst, row1 = src
    const float* ew   = (const float*)d_in[2];   // [N_EDGES]
    float*       out  = (float*)d_out;

    const int* dst = eidx;
    const int* src = eidx + N_EDGES;

    // workspace layout (~55 MB)
    char* ws = (char*)d_ws;
    size_t off = 0;
    u16*      xs      = (u16*)     (ws + off); off += align_up((size_t)N_NODES * N_GENES * 2, 256);
    u16*      hsA     = (u16*)     (ws + off); off += align_up((size_t)N_NODES * N_GENES * 2, 256);
    unsigned* meta    = (unsigned*)(ws + off); off += align_up((size_t)N_EDGES * 4, 256);
    int*      counts  = (int*)     (ws + off); off += align_up((size_t)N_NODES * 4, 256);
    int*      offsets = (int*)     (ws + off); off += align_up((size_t)(N_NODES + 1) * 4, 256);
    int*      cursor  = (int*)     (ws + off); off += align_up((size_t)N_NODES * 4, 256);
    int*      bsums   = (int*)     (ws + off); off += align_up((size_t)N_SCAN_BLKS * 4, 256);
    int*      bpref   = (int*)     (ws + off); off += align_up((size_t)N_SCAN_BLKS * 4, 256);
    (void)ws_size;

    u16* hsB = (u16*)d_out;   // d_out doubles as bf16 slice-major scratch (25.6 MB)

    // ---- build CSR by destination + slice-major bf16 copy of x ----
    hipMemsetAsync(counts, 0, (size_t)N_NODES * 4, stream);
    hist_kernel<<<(N_EDGES + 255) / 256, 256, 0, stream>>>(dst, counts);
    scan1_kernel<<<N_SCAN_BLKS, SCAN_BLK, 0, stream>>>(counts, offsets, bsums);
    scan2_kernel<<<1, 64, 0, stream>>>(bsums, bpref, &offsets[N_NODES]);
    scan3_kernel<<<N_SCAN_BLKS, SCAN_BLK, 0, stream>>>(offsets, bpref, cursor);
    scatter_kernel<<<(N_EDGES + 255) / 256, 256, 0, stream>>>(dst, src, ew, cursor, meta);
    cvt_slice_kernel<<<(N_NODES * N_GENES / 8 + 255) / 256, 256, 0, stream>>>(x, xs);

    // ---- 10 sliced propagation iterations ----
    // it0 reads xs; even it -> hsA, odd it -> hsB (d_out scratch); it8 -> hsA.
    // it9 (final) reads hsA, clamps with f32 x, writes f32 node-major d_out.
    const u16* hin = xs;
    for (int it = 0; it < NUM_ITERS - 1; ++it) {
        u16* hout = (it & 1) ? hsB : hsA;
        prop8_b<<<PROP_GRID, 256, 0, stream>>>(hin, xs, offsets, meta, hout);
        hin = hout;
    }
    prop8_final<<<PROP_GRID, 256, 0, stream>>>(hin, x, offsets, meta, out);
}

// Round 10
// 1356.985 us; speedup vs baseline: 1.1994x; 1.1994x over previous
//
#include <hip/hip_runtime.h>

#define N_NODES 50000
#define N_GENES 256
#define N_EDGES 800000
#define NUM_ITERS 10
#define SCAN_BLK 1024
#define N_SCAN_BLKS ((N_NODES + SCAN_BLK - 1) / SCAN_BLK)   // 49

#define SLICE_G 32                    // genes/slice; bf16 slice = 3.2 MB < 4 MB L2
#define NODES_PER_WAVE 8              // one dst node per 8-lane group
#define NODES_PER_BLOCK 32            // 4 waves
#define BLKS_PER_SLICE ((N_NODES + NODES_PER_BLOCK - 1) / NODES_PER_BLOCK)  // 1563
#define PROP_GRID (BLKS_PER_SLICE * 8)                                      // 12504

typedef unsigned short u16;
struct u16x4 { u16 x, y, z, w; };

static __device__ __forceinline__ float bf2f(u16 b) {
    return __uint_as_float(((unsigned)b) << 16);
}
static __device__ __forceinline__ u16 f2bf(float f) {
    unsigned u = __float_as_uint(f);
    return (u16)((u + 0x7fffu + ((u >> 16) & 1u)) >> 16);   // RNE
}

// ---------------- CSR build (once per launch) -----------------------------

__global__ void hist_kernel(const int* __restrict__ dst, int* __restrict__ counts) {
    int e = blockIdx.x * blockDim.x + threadIdx.x;
    if (e < N_EDGES) atomicAdd(&counts[dst[e]], 1);
}

__global__ __launch_bounds__(SCAN_BLK) void scan1_kernel(
        const int* __restrict__ counts, int* __restrict__ offs,
        int* __restrict__ bsums) {
    int i = blockIdx.x * SCAN_BLK + threadIdx.x;
    int lane = threadIdx.x & 63, wid = threadIdx.x >> 6;
    int v = (i < N_NODES) ? counts[i] : 0;
    int x = v;
    #pragma unroll
    for (int o = 1; o < 64; o <<= 1) {
        int t = __shfl_up(x, o, 64);
        if (lane >= o) x += t;
    }
    __shared__ int wsum[16];
    if (lane == 63) wsum[wid] = x;
    __syncthreads();
    if (wid == 0 && lane < 16) {
        int y = wsum[lane];
        #pragma unroll
        for (int o = 1; o < 16; o <<= 1) {
            int t = __shfl_up(y, o, 64);
            if (lane >= o) y += t;
        }
        wsum[lane] = y;
    }
    __syncthreads();
    int pref = (wid > 0) ? wsum[wid - 1] : 0;
    int incl = x + pref;
    if (i < N_NODES) offs[i] = incl - v;
    if (threadIdx.x == SCAN_BLK - 1) bsums[blockIdx.x] = incl;
}

__global__ void scan2_kernel(const int* __restrict__ bsums,
                             int* __restrict__ bpref,
                             int* __restrict__ offs_total) {
    int lane = threadIdx.x;  // 64 threads
    int v = (lane < N_SCAN_BLKS) ? bsums[lane] : 0;
    int x = v;
    #pragma unroll
    for (int o = 1; o < 64; o <<= 1) {
        int t = __shfl_up(x, o, 64);
        if (lane >= o) x += t;
    }
    if (lane < N_SCAN_BLKS) bpref[lane] = x - v;
    if (lane == 63) offs_total[0] = x;
}

__global__ __launch_bounds__(SCAN_BLK) void scan3_kernel(
        int* __restrict__ offs, const int* __restrict__ bpref,
        int* __restrict__ cursor) {
    int i = blockIdx.x * SCAN_BLK + threadIdx.x;
    if (i < N_NODES) {
        int o = offs[i] + bpref[blockIdx.x];
        offs[i] = o;
        cursor[i] = o;
    }
}

// CSR payload: 4B/edge meta = u16 src | bf16(w) << 16
__global__ void scatter_kernel(const int* __restrict__ dst,
                               const int* __restrict__ src,
                               const float* __restrict__ w,
                               int* __restrict__ cursor,
                               unsigned* __restrict__ meta) {
    int e = blockIdx.x * blockDim.x + threadIdx.x;
    if (e < N_EDGES) {
        int d = dst[e];
        int p = atomicAdd(&cursor[d], 1);
        meta[p] = (unsigned)(u16)src[e] | ((unsigned)f2bf(w[e]) << 16);
    }
}

// ---- degree binning: counting-sort node ids by (clamped) degree ----------
__global__ void deg_hist_kernel(const int* __restrict__ offsets,
                                int* __restrict__ dcount) {
    int i = blockIdx.x * blockDim.x + threadIdx.x;
    if (i < N_NODES) {
        int d = offsets[i + 1] - offsets[i];
        if (d > 63) d = 63;
        atomicAdd(&dcount[d], 1);
    }
}

__global__ void deg_scan_kernel(const int* __restrict__ dcount,
                                int* __restrict__ dcursor) {
    int lane = threadIdx.x;  // 64
    int v = dcount[lane];
    int x = v;
    #pragma unroll
    for (int o = 1; o < 64; o <<= 1) {
        int t = __shfl_up(x, o, 64);
        if (lane >= o) x += t;
    }
    dcursor[lane] = x - v;   // exclusive prefix
}

__global__ void deg_scatter_kernel(const int* __restrict__ offsets,
                                   int* __restrict__ dcursor,
                                   int* __restrict__ perm) {
    int i = blockIdx.x * blockDim.x + threadIdx.x;
    if (i < N_NODES) {
        int d = offsets[i + 1] - offsets[i];
        if (d > 63) d = 63;
        int pos = atomicAdd(&dcursor[d], 1);
        perm[pos] = i;
    }
}

// x (f32 node-major) -> xs (bf16 slice-major [8][N][32]); 8 genes per thread
__global__ __launch_bounds__(256) void cvt_slice_kernel(const float* __restrict__ x,
                                                        u16* __restrict__ xs) {
    int base = (blockIdx.x * blockDim.x + threadIdx.x) * 8;
    if (base >= N_NODES * N_GENES) return;
    int node = base >> 8;
    int gene = base & 255;
    int slice = gene >> 5;
    int g = gene & 31;             // 8-aligned within slice
    float4 a = *reinterpret_cast<const float4*>(&x[base]);
    float4 b = *reinterpret_cast<const float4*>(&x[base + 4]);
    u16x4 r0 = { f2bf(a.x), f2bf(a.y), f2bf(a.z), f2bf(a.w) };
    u16x4 r1 = { f2bf(b.x), f2bf(b.y), f2bf(b.z), f2bf(b.w) };
    size_t o = (size_t)slice * (N_NODES * SLICE_G) + (size_t)node * SLICE_G + g;
    *reinterpret_cast<u16x4*>(&xs[o])     = r0;
    *reinterpret_cast<u16x4*>(&xs[o + 4]) = r1;
}

// ---------------- XCD-pinned sliced propagation, group-per-node -----------
// Slice s (3.2 MB bf16) touched only by blocks with blockIdx%8 == s -> L2
// resident per XCD. Wave = 8 groups x 8 lanes; EACH GROUP OWNS ONE DST NODE
// (lane sub owns genes sub*4..sub*4+3 -> accumulator IS the output: no
// cross-lane reduce). Per step each group processes one edge -> wave does 8
// edges/step, branchless (padded meta==0 -> w=+0). Nodes are degree-binned
// via perm so co-waved nodes have near-equal degree (no divergence waste).

__global__ __launch_bounds__(256) void prop8_b(
        const u16* __restrict__ hin,   // [8][N][32]
        const u16* __restrict__ xs,    // [8][N][32]
        const int* __restrict__ offsets,
        const int* __restrict__ perm,
        const unsigned* __restrict__ meta,
        u16* __restrict__ out) {       // [8][N][32]
    int slice = blockIdx.x & 7;
    int blk   = blockIdx.x >> 3;
    int wid = threadIdx.x >> 6, lane = threadIdx.x & 63;
    int g = lane >> 3, sub = lane & 7;
    int widx = blk * NODES_PER_BLOCK + wid * NODES_PER_WAVE + g;
    bool valid = widx < N_NODES;
    int p = valid ? perm[widx] : 0;
    int beg = offsets[p];
    int deg = valid ? (offsets[p + 1] - beg) : 0;
    // wave max degree (deg uniform within group)
    int dmax = deg;
    dmax = max(dmax, __shfl_xor(dmax, 8));
    dmax = max(dmax, __shfl_xor(dmax, 16));
    dmax = max(dmax, __shfl_xor(dmax, 32));

    const u16* hs = hin + (size_t)slice * (N_NODES * SLICE_G);
    float a0 = 0.f, a1 = 0.f, a2 = 0.f, a3 = 0.f;
    float b0 = 0.f, b1 = 0.f, b2 = 0.f, b3 = 0.f;
    int lanebase = lane & ~7;   // g*8

    for (int cb = 0; cb < dmax; cb += 8) {
        unsigned mv = 0;
        if (cb + sub < deg) mv = __builtin_nontemporal_load(&meta[beg + cb + sub]);
        #pragma unroll
        for (int e = 0; e < 8; e += 2) {
            unsigned m0 = __shfl(mv, lanebase + e);
            unsigned m1 = __shfl(mv, lanebase + e + 1);
            float w0 = bf2f((u16)(m0 >> 16));
            float w1 = bf2f((u16)(m1 >> 16));
            int s0 = (int)(m0 & 0xFFFFu);
            int s1 = (int)(m1 & 0xFFFFu);
            u16x4 r0 = *reinterpret_cast<const u16x4*>(&hs[s0 * SLICE_G + sub * 4]);
            u16x4 r1 = *reinterpret_cast<const u16x4*>(&hs[s1 * SLICE_G + sub * 4]);
            a0 += w0 * bf2f(r0.x); a1 += w0 * bf2f(r0.y);
            a2 += w0 * bf2f(r0.z); a3 += w0 * bf2f(r0.w);
            b0 += w1 * bf2f(r1.x); b1 += w1 * bf2f(r1.y);
            b2 += w1 * bf2f(r1.z); b3 += w1 * bf2f(r1.w);
        }
    }
    a0 += b0; a1 += b1; a2 += b2; a3 += b3;

    if (valid) {
        size_t o = (size_t)slice * (N_NODES * SLICE_G) + (size_t)p * SLICE_G + sub * 4;
        u16x4 ox = *reinterpret_cast<const u16x4*>(&xs[o]);
        u16x4 res;
        res.x = ox.x ? ox.x : f2bf(a0);   // x >= 0: bits==0 <=> value==0
        res.y = ox.y ? ox.y : f2bf(a1);
        res.z = ox.z ? ox.z : f2bf(a2);
        res.w = ox.w ? ox.w : f2bf(a3);
        *reinterpret_cast<u16x4*>(&out[o]) = res;
    }
}

// Final iteration: same structure; clamp with pristine f32 x, write f32
// node-major output.
__global__ __launch_bounds__(256) void prop8_final(
        const u16* __restrict__ hin,
        const float* __restrict__ x,
        const int* __restrict__ offsets,
        const int* __restrict__ perm,
        const unsigned* __restrict__ meta,
        float* __restrict__ out) {
    int slice = blockIdx.x & 7;
    int blk   = blockIdx.x >> 3;
    int wid = threadIdx.x >> 6, lane = threadIdx.x & 63;
    int g = lane >> 3, sub = lane & 7;
    int widx = blk * NODES_PER_BLOCK + wid * NODES_PER_WAVE + g;
    bool valid = widx < N_NODES;
    int p = valid ? perm[widx] : 0;
    int beg = offsets[p];
    int deg = valid ? (offsets[p + 1] - beg) : 0;
    int dmax = deg;
    dmax = max(dmax, __shfl_xor(dmax, 8));
    dmax = max(dmax, __shfl_xor(dmax, 16));
    dmax = max(dmax, __shfl_xor(dmax, 32));

    const u16* hs = hin + (size_t)slice * (N_NODES * SLICE_G);
    float a0 = 0.f, a1 = 0.f, a2 = 0.f, a3 = 0.f;
    float b0 = 0.f, b1 = 0.f, b2 = 0.f, b3 = 0.f;
    int lanebase = lane & ~7;

    for (int cb = 0; cb < dmax; cb += 8) {
        unsigned mv = 0;
        if (cb + sub < deg) mv = __builtin_nontemporal_load(&meta[beg + cb + sub]);
        #pragma unroll
        for (int e = 0; e < 8; e += 2) {
            unsigned m0 = __shfl(mv, lanebase + e);
            unsigned m1 = __shfl(mv, lanebase + e + 1);
            float w0 = bf2f((u16)(m0 >> 16));
            float w1 = bf2f((u16)(m1 >> 16));
            int s0 = (int)(m0 & 0xFFFFu);
            int s1 = (int)(m1 & 0xFFFFu);
            u16x4 r0 = *reinterpret_cast<const u16x4*>(&hs[s0 * SLICE_G + sub * 4]);
            u16x4 r1 = *reinterpret_cast<const u16x4*>(&hs[s1 * SLICE_G + sub * 4]);
            a0 += w0 * bf2f(r0.x); a1 += w0 * bf2f(r0.y);
            a2 += w0 * bf2f(r0.z); a3 += w0 * bf2f(r0.w);
            b0 += w1 * bf2f(r1.x); b1 += w1 * bf2f(r1.y);
            b2 += w1 * bf2f(r1.z); b3 += w1 * bf2f(r1.w);
        }
    }
    a0 += b0; a1 += b1; a2 += b2; a3 += b3;

    if (valid) {
        size_t xo = (size_t)p * N_GENES + slice * SLICE_G + sub * 4;
        float4 o = *reinterpret_cast<const float4*>(&x[xo]);
        float4 r;
        r.x = (o.x != 0.f) ? o.x : a0;
        r.y = (o.y != 0.f) ? o.y : a1;
        r.z = (o.z != 0.f) ? o.z : a2;
        r.w = (o.w != 0.f) ? o.w : a3;
        *reinterpret_cast<float4*>(&out[xo]) = r;
    }
}

// --------------------------------------------------------------------------

static inline size_t align_up(size_t x, size_t a) { return (x + a - 1) & ~(a - 1); }

extern "C" void kernel_launch(void* const* d_in, const int* in_sizes, int n_in,
                              void* d_out, int out_size, void* d_ws, size_t ws_size,
                              hipStream_t stream) {
    const float* x    = (const float*)d_in[0];   // [N_NODES, N_GENES]
    const int*   eidx = (const int*)d_in[1];     // [2, N_EDGES]: row0 = dst, row1 = src
    const float* ew   = (const float*)d_in[2];   // [N_EDGES]
    float*       out  = (float*)d_out;

    const int* dst = eidx;
    const int* src = eidx + N_EDGES;

    // workspace layout (~56 MB)
    char* ws = (char*)d_ws;
    size_t off = 0;
    u16*      xs      = (u16*)     (ws + off); off += align_up((size_t)N_NODES * N_GENES * 2, 256);
    u16*      hsA     = (u16*)     (ws + off); off += align_up((size_t)N_NODES * N_GENES * 2, 256);
    unsigned* meta    = (unsigned*)(ws + off); off += align_up((size_t)N_EDGES * 4, 256);
    int*      counts  = (int*)     (ws + off); off += align_up((size_t)N_NODES * 4, 256);
    int*      offsets = (int*)     (ws + off); off += align_up((size_t)(N_NODES + 1) * 4, 256);
    int*      cursor  = (int*)     (ws + off); off += align_up((size_t)N_NODES * 4, 256);
    int*      perm    = (int*)     (ws + off); off += align_up((size_t)N_NODES * 4, 256);
    int*      bsums   = (int*)     (ws + off); off += align_up((size_t)N_SCAN_BLKS * 4, 256);
    int*      bpref   = (int*)     (ws + off); off += align_up((size_t)N_SCAN_BLKS * 4, 256);
    int*      dcount  = (int*)     (ws + off); off += align_up(64 * 4, 256);
    int*      dcursor = (int*)     (ws + off); off += align_up(64 * 4, 256);
    (void)ws_size;

    u16* hsB = (u16*)d_out;   // d_out doubles as bf16 slice-major scratch (25.6 MB)

    // ---- build CSR by destination + degree binning + bf16 slice copy ----
    hipMemsetAsync(counts, 0, (size_t)N_NODES * 4, stream);
    hipMemsetAsync(dcount, 0, 64 * 4, stream);
    hist_kernel<<<(N_EDGES + 255) / 256, 256, 0, stream>>>(dst, counts);
    scan1_kernel<<<N_SCAN_BLKS, SCAN_BLK, 0, stream>>>(counts, offsets, bsums);
    scan2_kernel<<<1, 64, 0, stream>>>(bsums, bpref, &offsets[N_NODES]);
    scan3_kernel<<<N_SCAN_BLKS, SCAN_BLK, 0, stream>>>(offsets, bpref, cursor);
    scatter_kernel<<<(N_EDGES + 255) / 256, 256, 0, stream>>>(dst, src, ew, cursor, meta);
    deg_hist_kernel<<<(N_NODES + 255) / 256, 256, 0, stream>>>(offsets, dcount);
    deg_scan_kernel<<<1, 64, 0, stream>>>(dcount, dcursor);
    deg_scatter_kernel<<<(N_NODES + 255) / 256, 256, 0, stream>>>(offsets, dcursor, perm);
    cvt_slice_kernel<<<(N_NODES * N_GENES / 8 + 255) / 256, 256, 0, stream>>>(x, xs);

    // ---- 10 sliced propagation iterations ----
    // it0 reads xs; even it -> hsA, odd it -> hsB (d_out scratch); it8 -> hsA.
    // it9 (final) reads hsA, clamps with f32 x, writes f32 node-major d_out.
    const u16* hin = xs;
    for (int it = 0; it < NUM_ITERS - 1; ++it) {
        u16* hout = (it & 1) ? hsB : hsA;
        prop8_b<<<PROP_GRID, 256, 0, stream>>>(hin, xs, offsets, perm, meta, hout);
        hin = hout;
    }
    prop8_final<<<PROP_GRID, 256, 0, stream>>>(hin, x, offsets, perm, meta, out);
}

// Round 11
// 762.293 us; speedup vs baseline: 2.1350x; 1.7801x over previous
//
#include <hip/hip_runtime.h>

#define N_NODES 50000
#define N_GENES 256
#define N_EDGES 800000
#define NUM_ITERS 10
#define SCAN_BLK 1024
#define N_SCAN_BLKS ((N_NODES + SCAN_BLK - 1) / SCAN_BLK)   // 49

#define SLICE_G 128                   // genes/slice (bf16 slice = 12.8 MB / 4-XCD group)
#define PROP_GRID 25000               // 2 slices x 12500 blocks (4 nodes/block)

typedef unsigned short u16;
struct u16x4 { u16 x, y, z, w; };

static __device__ __forceinline__ float bf2f(u16 b) {
    return __uint_as_float(((unsigned)b) << 16);
}
static __device__ __forceinline__ u16 f2bf(float f) {
    unsigned u = __float_as_uint(f);
    return (u16)((u + 0x7fffu + ((u >> 16) & 1u)) >> 16);   // RNE
}

// ---------------- CSR build (once per launch) -----------------------------

__global__ void hist_kernel(const int* __restrict__ dst, int* __restrict__ counts) {
    int e = blockIdx.x * blockDim.x + threadIdx.x;
    if (e < N_EDGES) atomicAdd(&counts[dst[e]], 1);
}

__global__ __launch_bounds__(SCAN_BLK) void scan1_kernel(
        const int* __restrict__ counts, int* __restrict__ offs,
        int* __restrict__ bsums) {
    int i = blockIdx.x * SCAN_BLK + threadIdx.x;
    int lane = threadIdx.x & 63, wid = threadIdx.x >> 6;
    int v = (i < N_NODES) ? counts[i] : 0;
    int x = v;
    #pragma unroll
    for (int o = 1; o < 64; o <<= 1) {
        int t = __shfl_up(x, o, 64);
        if (lane >= o) x += t;
    }
    __shared__ int wsum[16];
    if (lane == 63) wsum[wid] = x;
    __syncthreads();
    if (wid == 0 && lane < 16) {
        int y = wsum[lane];
        #pragma unroll
        for (int o = 1; o < 16; o <<= 1) {
            int t = __shfl_up(y, o, 64);
            if (lane >= o) y += t;
        }
        wsum[lane] = y;
    }
    __syncthreads();
    int pref = (wid > 0) ? wsum[wid - 1] : 0;
    int incl = x + pref;
    if (i < N_NODES) offs[i] = incl - v;
    if (threadIdx.x == SCAN_BLK - 1) bsums[blockIdx.x] = incl;
}

__global__ void scan2_kernel(const int* __restrict__ bsums,
                             int* __restrict__ bpref,
                             int* __restrict__ offs_total) {
    int lane = threadIdx.x;  // 64 threads
    int v = (lane < N_SCAN_BLKS) ? bsums[lane] : 0;
    int x = v;
    #pragma unroll
    for (int o = 1; o < 64; o <<= 1) {
        int t = __shfl_up(x, o, 64);
        if (lane >= o) x += t;
    }
    if (lane < N_SCAN_BLKS) bpref[lane] = x - v;
    if (lane == 63) offs_total[0] = x;
}

__global__ __launch_bounds__(SCAN_BLK) void scan3_kernel(
        int* __restrict__ offs, const int* __restrict__ bpref,
        int* __restrict__ cursor) {
    int i = blockIdx.x * SCAN_BLK + threadIdx.x;
    if (i < N_NODES) {
        int o = offs[i] + bpref[blockIdx.x];
        offs[i] = o;
        cursor[i] = o;
    }
}

// CSR payload: 4B/edge meta = u16 src | bf16(w) << 16
__global__ void scatter_kernel(const int* __restrict__ dst,
                               const int* __restrict__ src,
                               const float* __restrict__ w,
                               int* __restrict__ cursor,
                               unsigned* __restrict__ meta) {
    int e = blockIdx.x * blockDim.x + threadIdx.x;
    if (e < N_EDGES) {
        int d = dst[e];
        int p = atomicAdd(&cursor[d], 1);
        meta[p] = (unsigned)(u16)src[e] | ((unsigned)f2bf(w[e]) << 16);
    }
}

// x (f32 node-major) -> xs (bf16 slice-major [2][N][128]); 8 genes per thread
__global__ __launch_bounds__(256) void cvt_slice_kernel(const float* __restrict__ x,
                                                        u16* __restrict__ xs) {
    int base = (blockIdx.x * blockDim.x + threadIdx.x) * 8;
    if (base >= N_NODES * N_GENES) return;
    int node = base >> 8;
    int gene = base & 255;
    int slice = gene >> 7;
    int g = gene & 127;            // 8-aligned within slice
    float4 a = *reinterpret_cast<const float4*>(&x[base]);
    float4 b = *reinterpret_cast<const float4*>(&x[base + 4]);
    u16x4 r0 = { f2bf(a.x), f2bf(a.y), f2bf(a.z), f2bf(a.w) };
    u16x4 r1 = { f2bf(b.x), f2bf(b.y), f2bf(b.z), f2bf(b.w) };
    size_t o = (size_t)slice * (N_NODES * SLICE_G) + (size_t)node * SLICE_G + g;
    *reinterpret_cast<u16x4*>(&xs[o])     = r0;
    *reinterpret_cast<u16x4*>(&xs[o + 4]) = r1;
}

// ---------------- 2-slice propagation, half-wave per edge -----------------
// Slice s (128 genes bf16, 12.8 MB) is touched only by blocks on XCD group s
// (blockIdx%8<4 -> slice 0) -> near-resident in the group's L2s (r8 measured
// h-fill ~1.17x compulsory). One wave per (node, slice); lane = 32*half +
// gene-quad: each HALF-WAVE processes one edge (32 lanes x u16x4 = 128 genes,
// 256B contiguous) -> 2 edges per load-issue, one bpermute per 2 edges
// (4B meta = u16 src | bf16 w). 4-step unroll = 4 loads in flight per lane.
// Branchless padding: lane>=cnt has meta 0 -> w=+0, src=0 (harmless FMA).

__global__ __launch_bounds__(256) void prop2_b(
        const u16* __restrict__ hin,   // [2][N][128]
        const u16* __restrict__ xs,    // [2][N][128]
        const int* __restrict__ offsets,
        const unsigned* __restrict__ meta,
        u16* __restrict__ out) {       // [2][N][128]
    int b = blockIdx.x;
    int slice = ((b & 7) < 4) ? 0 : 1;
    int idx = (b >> 3) * 4 + (b & 3);            // 0..12499 within slice
    int node = idx * 4 + (threadIdx.x >> 6);     // 12500*4 = 50000 exact
    int lane = threadIdx.x & 63;
    int half = lane >> 5;                        // 0/1: which edge of the pair
    int g4 = (lane & 31) << 2;                   // genes g4..g4+3 within slice

    const u16* hs = hin + (size_t)slice * (N_NODES * SLICE_G);
    int beg = offsets[node], end = offsets[node + 1];
    float a0 = 0.f, a1 = 0.f, a2 = 0.f, a3 = 0.f;
    float c0 = 0.f, c1 = 0.f, c2 = 0.f, c3 = 0.f;

    for (int base = beg; base < end; base += 64) {
        int cnt = end - base;
        if (cnt > 64) cnt = 64;
        unsigned mv = 0;
        if (lane < cnt) mv = __builtin_nontemporal_load(&meta[base + lane]);
        int nsteps = (cnt + 1) >> 1;             // 2 edges per step
        int k = 0;
        for (; k + 4 <= nsteps; k += 4) {
            unsigned m0 = __shfl(mv, 2 * k + half);
            unsigned m1 = __shfl(mv, 2 * k + 2 + half);
            unsigned m2 = __shfl(mv, 2 * k + 4 + half);
            unsigned m3 = __shfl(mv, 2 * k + 6 + half);
            float w0 = bf2f((u16)(m0 >> 16)), w1 = bf2f((u16)(m1 >> 16));
            float w2 = bf2f((u16)(m2 >> 16)), w3 = bf2f((u16)(m3 >> 16));
            int s0 = (int)(m0 & 0xFFFFu), s1 = (int)(m1 & 0xFFFFu);
            int s2 = (int)(m2 & 0xFFFFu), s3 = (int)(m3 & 0xFFFFu);
            u16x4 r0 = *reinterpret_cast<const u16x4*>(&hs[s0 * SLICE_G + g4]);
            u16x4 r1 = *reinterpret_cast<const u16x4*>(&hs[s1 * SLICE_G + g4]);
            u16x4 r2 = *reinterpret_cast<const u16x4*>(&hs[s2 * SLICE_G + g4]);
            u16x4 r3 = *reinterpret_cast<const u16x4*>(&hs[s3 * SLICE_G + g4]);
            a0 += w0 * bf2f(r0.x); a1 += w0 * bf2f(r0.y);
            a2 += w0 * bf2f(r0.z); a3 += w0 * bf2f(r0.w);
            c0 += w1 * bf2f(r1.x); c1 += w1 * bf2f(r1.y);
            c2 += w1 * bf2f(r1.z); c3 += w1 * bf2f(r1.w);
            a0 += w2 * bf2f(r2.x); a1 += w2 * bf2f(r2.y);
            a2 += w2 * bf2f(r2.z); a3 += w2 * bf2f(r2.w);
            c0 += w3 * bf2f(r3.x); c1 += w3 * bf2f(r3.y);
            c2 += w3 * bf2f(r3.z); c3 += w3 * bf2f(r3.w);
        }
        for (; k < nsteps; ++k) {
            unsigned m = __shfl(mv, 2 * k + half);
            float w = bf2f((u16)(m >> 16));
            int s = (int)(m & 0xFFFFu);
            u16x4 r = *reinterpret_cast<const u16x4*>(&hs[s * SLICE_G + g4]);
            a0 += w * bf2f(r.x); a1 += w * bf2f(r.y);
            a2 += w * bf2f(r.z); a3 += w * bf2f(r.w);
        }
    }
    // merge the two half-wave edge streams (gene position identical)
    a0 += c0; a1 += c1; a2 += c2; a3 += c3;
    a0 += __shfl_xor(a0, 32); a1 += __shfl_xor(a1, 32);
    a2 += __shfl_xor(a2, 32); a3 += __shfl_xor(a3, 32);

    if (half == 0) {
        size_t o = (size_t)slice * (N_NODES * SLICE_G) + (size_t)node * SLICE_G + g4;
        u16x4 ox = *reinterpret_cast<const u16x4*>(&xs[o]);
        u16x4 res;
        res.x = ox.x ? ox.x : f2bf(a0);   // x >= 0: bits==0 <=> value==0
        res.y = ox.y ? ox.y : f2bf(a1);
        res.z = ox.z ? ox.z : f2bf(a2);
        res.w = ox.w ? ox.w : f2bf(a3);
        *reinterpret_cast<u16x4*>(&out[o]) = res;
    }
}

// Final iteration: same gather; clamp with pristine f32 x, write f32
// node-major output.
__global__ __launch_bounds__(256) void prop2_final(
        const u16* __restrict__ hin,
        const float* __restrict__ x,
        const int* __restrict__ offsets,
        const unsigned* __restrict__ meta,
        float* __restrict__ out) {
    int b = blockIdx.x;
    int slice = ((b & 7) < 4) ? 0 : 1;
    int idx = (b >> 3) * 4 + (b & 3);
    int node = idx * 4 + (threadIdx.x >> 6);
    int lane = threadIdx.x & 63;
    int half = lane >> 5;
    int g4 = (lane & 31) << 2;

    const u16* hs = hin + (size_t)slice * (N_NODES * SLICE_G);
    int beg = offsets[node], end = offsets[node + 1];
    float a0 = 0.f, a1 = 0.f, a2 = 0.f, a3 = 0.f;
    float c0 = 0.f, c1 = 0.f, c2 = 0.f, c3 = 0.f;

    for (int base = beg; base < end; base += 64) {
        int cnt = end - base;
        if (cnt > 64) cnt = 64;
        unsigned mv = 0;
        if (lane < cnt) mv = __builtin_nontemporal_load(&meta[base + lane]);
        int nsteps = (cnt + 1) >> 1;
        int k = 0;
        for (; k + 4 <= nsteps; k += 4) {
            unsigned m0 = __shfl(mv, 2 * k + half);
            unsigned m1 = __shfl(mv, 2 * k + 2 + half);
            unsigned m2 = __shfl(mv, 2 * k + 4 + half);
            unsigned m3 = __shfl(mv, 2 * k + 6 + half);
            float w0 = bf2f((u16)(m0 >> 16)), w1 = bf2f((u16)(m1 >> 16));
            float w2 = bf2f((u16)(m2 >> 16)), w3 = bf2f((u16)(m3 >> 16));
            int s0 = (int)(m0 & 0xFFFFu), s1 = (int)(m1 & 0xFFFFu);
            int s2 = (int)(m2 & 0xFFFFu), s3 = (int)(m3 & 0xFFFFu);
            u16x4 r0 = *reinterpret_cast<const u16x4*>(&hs[s0 * SLICE_G + g4]);
            u16x4 r1 = *reinterpret_cast<const u16x4*>(&hs[s1 * SLICE_G + g4]);
            u16x4 r2 = *reinterpret_cast<const u16x4*>(&hs[s2 * SLICE_G + g4]);
            u16x4 r3 = *reinterpret_cast<const u16x4*>(&hs[s3 * SLICE_G + g4]);
            a0 += w0 * bf2f(r0.x); a1 += w0 * bf2f(r0.y);
            a2 += w0 * bf2f(r0.z); a3 += w0 * bf2f(r0.w);
            c0 += w1 * bf2f(r1.x); c1 += w1 * bf2f(r1.y);
            c2 += w1 * bf2f(r1.z); c3 += w1 * bf2f(r1.w);
            a0 += w2 * bf2f(r2.x); a1 += w2 * bf2f(r2.y);
            a2 += w2 * bf2f(r2.z); a3 += w2 * bf2f(r2.w);
            c0 += w3 * bf2f(r3.x); c1 += w3 * bf2f(r3.y);
            c2 += w3 * bf2f(r3.z); c3 += w3 * bf2f(r3.w);
        }
        for (; k < nsteps; ++k) {
            unsigned m = __shfl(mv, 2 * k + half);
            float w = bf2f((u16)(m >> 16));
            int s = (int)(m & 0xFFFFu);
            u16x4 r = *reinterpret_cast<const u16x4*>(&hs[s * SLICE_G + g4]);
            a0 += w * bf2f(r.x); a1 += w * bf2f(r.y);
            a2 += w * bf2f(r.z); a3 += w * bf2f(r.w);
        }
    }
    a0 += c0; a1 += c1; a2 += c2; a3 += c3;
    a0 += __shfl_xor(a0, 32); a1 += __shfl_xor(a1, 32);
    a2 += __shfl_xor(a2, 32); a3 += __shfl_xor(a3, 32);

    if (half == 0) {
        size_t xo = (size_t)node * N_GENES + slice * SLICE_G + g4;
        float4 o = *reinterpret_cast<const float4*>(&x[xo]);
        float4 r;
        r.x = (o.x != 0.f) ? o.x : a0;
        r.y = (o.y != 0.f) ? o.y : a1;
        r.z = (o.z != 0.f) ? o.z : a2;
        r.w = (o.w != 0.f) ? o.w : a3;
        *reinterpret_cast<float4*>(&out[xo]) = r;
    }
}

// --------------------------------------------------------------------------

static inline size_t align_up(size_t x, size_t a) { return (x + a - 1) & ~(a - 1); }

extern "C" void kernel_launch(void* const* d_in, const int* in_sizes, int n_in,
                              void* d_out, int out_size, void* d_ws, size_t ws_size,
                              hipStream_t stream) {
    const float* x    = (const float*)d_in[0];   // [N_NODES, N_GENES]
    const int*   eidx = (const int*)d_in[1];     // [2, N_EDGES]: row0 = dst, row1 = src
    const float* ew   = (const float*)d_in[2];   // [N_EDGES]
    float*       out  = (float*)d_out;

    const int* dst = eidx;
    const int* src = eidx + N_EDGES;

    // workspace layout (~55 MB)
    char* ws = (char*)d_ws;
    size_t off = 0;
    u16*      xs      = (u16*)     (ws + off); off += align_up((size_t)N_NODES * N_GENES * 2, 256);
    u16*      hsA     = (u16*)     (ws + off); off += align_up((size_t)N_NODES * N_GENES * 2, 256);
    unsigned* meta    = (unsigned*)(ws + off); off += align_up((size_t)N_EDGES * 4, 256);
    int*      counts  = (int*)     (ws + off); off += align_up((size_t)N_NODES * 4, 256);
    int*      offsets = (int*)     (ws + off); off += align_up((size_t)(N_NODES + 1) * 4, 256);
    int*      cursor  = (int*)     (ws + off); off += align_up((size_t)N_NODES * 4, 256);
    int*      bsums   = (int*)     (ws + off); off += align_up((size_t)N_SCAN_BLKS * 4, 256);
    int*      bpref   = (int*)     (ws + off); off += align_up((size_t)N_SCAN_BLKS * 4, 256);
    (void)ws_size;

    u16* hsB = (u16*)d_out;   // d_out doubles as bf16 slice-major scratch (25.6 MB)

    // ---- build CSR by destination + slice-major bf16 copy of x ----
    hipMemsetAsync(counts, 0, (size_t)N_NODES * 4, stream);
    hist_kernel<<<(N_EDGES + 255) / 256, 256, 0, stream>>>(dst, counts);
    scan1_kernel<<<N_SCAN_BLKS, SCAN_BLK, 0, stream>>>(counts, offsets, bsums);
    scan2_kernel<<<1, 64, 0, stream>>>(bsums, bpref, &offsets[N_NODES]);
    scan3_kernel<<<N_SCAN_BLKS, SCAN_BLK, 0, stream>>>(offsets, bpref, cursor);
    scatter_kernel<<<(N_EDGES + 255) / 256, 256, 0, stream>>>(dst, src, ew, cursor, meta);
    cvt_slice_kernel<<<(N_NODES * N_GENES / 8 + 255) / 256, 256, 0, stream>>>(x, xs);

    // ---- 10 sliced propagation iterations ----
    // it0 reads xs; even it -> hsA, odd it -> hsB (d_out scratch); it8 -> hsA.
    // it9 (final) reads hsA, clamps with f32 x, writes f32 node-major d_out.
    const u16* hin = xs;
    for (int it = 0; it < NUM_ITERS - 1; ++it) {
        u16* hout = (it & 1) ? hsB : hsA;
        prop2_b<<<PROP_GRID, 256, 0, stream>>>(hin, xs, offsets, meta, hout);
        hin = hout;
    }
    prop2_final<<<PROP_GRID, 256, 0, stream>>>(hin, x, offsets, meta, out);
}